// Round 5
// baseline (129.174 us; speedup 1.0000x reference)
//
#include <hip/hip_runtime.h>
#include <stdint.h>

#define NBOX 8192
#define NW   128            // NBOX/64 words
#define IOU_THR 0.45f
#define ENT_CAP 65536u      // global entry capacity
#define ENT_LDS 2560        // LDS-staged entry capacity (40 KB)
#define MASK_BLOCKS 1024

typedef unsigned long long u64;
typedef unsigned int u32;

// ---------------- K1: rank parts + per-block box max + counter zero ----------------
// key = (~bits(score))<<32 | idx : ascending == (score desc, idx asc) == stable argsort(-scores)
// Each block computes keys LOCALLY from scores (pure function) -> no producer kernel needed.
// rank_part[ip][j] written non-atomically -> no zero-init needed.
__global__ void __launch_bounds__(256) k_prep(const float* __restrict__ scores,
                                              const float* __restrict__ boxes,
                                              int* __restrict__ rank_part,
                                              float* __restrict__ blockmax,
                                              u32* __restrict__ cursor, u32* __restrict__ done) {
    __shared__ u64 lk[1024];
    __shared__ float red[128];
    int t = threadIdx.x, b = blockIdx.x;
    int jc = b & 31, ip = b >> 5;
    for (int i = t; i < 1024; i += 256) {
        int gi = ip * 1024 + i;
        lk[i] = ((u64)(~__float_as_uint(scores[gi])) << 32) | (u32)gi;
    }
    if (t < 128) red[t] = boxes[b * 128 + t];     // 256 blocks x 128 = all 32768 coords
    __syncthreads();
    int j = jc * 256 + t;
    u64 kj = ((u64)(~__float_as_uint(scores[j])) << 32) | (u32)j;
    int cnt = 0;
#pragma unroll 8
    for (int i = 0; i < 1024; ++i) cnt += (lk[i] < kj) ? 1 : 0;
    rank_part[ip * NBOX + j] = cnt;
    // reduce 128 -> blockmax[b] (wave 0 only after one LDS fold)
    if (t < 64) red[t] = fmaxf(red[t], red[t + 64]);
    __syncthreads();
    if (t < 64) {
        float m = red[t];
        for (int d = 32; d > 0; d >>= 1) m = fmaxf(m, __shfl_down(m, d, 64));
        if (t == 0) blockmax[b] = m;
    }
    if (b == 0 && t == 0) { *cursor = 0u; *done = 0u; }
}

// ---------------- K2: scatter-gather: sb[rank[j]] = offset-box(j) ----------------
__global__ void __launch_bounds__(256) k_sgather(const float4* __restrict__ boxes4,
                                                 const int* __restrict__ idxs,
                                                 const int* __restrict__ rank_part,
                                                 const float* __restrict__ blockmax,
                                                 float4* __restrict__ sb, float* __restrict__ area,
                                                 int* __restrict__ order) {
    __shared__ float red[256];
    int t = threadIdx.x;
    red[t] = blockmax[t];
    __syncthreads();
    for (int s = 128; s > 0; s >>= 1) {
        if (t < s) red[t] = fmaxf(red[t], red[t + s]);
        __syncthreads();
    }
    float mc1 = red[0] + 1.0f;
    int j = blockIdx.x * 256 + t;
    int r = 0;
#pragma unroll
    for (int p = 0; p < 8; ++p) r += rank_part[p * NBOX + j];
    float4 bx = boxes4[j];
    float off = (float)idxs[j] * mc1;
    bx.x += off; bx.y += off; bx.z += off; bx.w += off;
    sb[r] = bx;
    area[r] = (bx.z - bx.x) * (bx.w - bx.y);   // area on OFFSET boxes, exactly like ref
    order[r] = j;
}

// ---------------- K3: sparse mask + last-block {Jacobi resolve + placement + output} ----------------
// entry.x = word (bit b = over(i=64w+b, j), i<j) ; entry.y = (j<<7)|w
__global__ void __launch_bounds__(256) k_mask_tail(const float4* __restrict__ sb,
                                                   const float* __restrict__ area,
                                                   const int* __restrict__ order,
                                                   const float4* __restrict__ boxes4,
                                                   const float* __restrict__ scores,
                                                   ulonglong2* __restrict__ ent,
                                                   u32* __restrict__ cursor, u32* __restrict__ done,
                                                   float* __restrict__ out) {
    __shared__ float4 ib[64];
    __shared__ float  ia[64];
    __shared__ u32 slast;
    int t = threadIdx.x;

    // ---- phase 1: mask tiles (4096 tiles / MASK_BLOCKS blocks) ----
    for (int k = 0; k < 4096 / MASK_BLOCKS; ++k) {
        int tile = blockIdx.x + k * MASK_BLOCKS;
        int w = tile & 127, jc = tile >> 7;
        if (w * 64 >= jc * 256 + 255) continue;       // uniform per block: no i<j anywhere in tile
        __syncthreads();                              // protect ib/ia reuse across tiles
        if (t < 64) { ib[t] = sb[w * 64 + t]; ia[t] = area[w * 64 + t]; }
        __syncthreads();
        int j = jc * 256 + t;
        if (w * 64 < j) {
            float4 bj = sb[j];
            float  aj = area[j];
            u64 word = 0;
            int nb = min(64, j - w * 64);
            for (int bb = 0; bb < nb; ++bb) {
                float4 bi = ib[bb];
                float ltx = fmaxf(bi.x, bj.x), lty = fmaxf(bi.y, bj.y);
                float rbx = fminf(bi.z, bj.z), rby = fminf(bi.w, bj.w);
                float wx = fmaxf(rbx - ltx, 0.0f), wy = fmaxf(rby - lty, 0.0f);
                float inter = wx * wy;
                if (inter > 0.0f) {                   // iou==0 can never exceed thr
                    float iou = inter / (ia[bb] + aj - inter);   // IEEE f32 div, matches ref
                    if (iou > IOU_THR) word |= (1ULL << bb);
                }
            }
            if (word) {
                u32 idx = atomicAdd(cursor, 1u);
                if (idx < ENT_CAP) {
                    ulonglong2 e; e.x = word; e.y = (u64)(((u32)j << 7) | (u32)w);
                    ent[idx] = e;
                }
            }
        }
    }

    // ---- last-block gate (release: per-thread fence, then block-joined publish) ----
    __threadfence();
    __syncthreads();
    if (t == 0) slast = (atomicAdd(done, 1u) == (u32)gridDim.x - 1u) ? 1u : 0u;
    __syncthreads();
    if (!slast) return;
    __threadfence();                                  // acquire side

    // ---- phase 2 (one block): Jacobi fixpoint of greedy NMS over sparse entries ----
    // kept[j] = !exists i<j : kept[i] && over(i,j). Unique fixpoint; stability == exact greedy.
    __shared__ u64 kw[NW], sup[NW], ko[NW];
    __shared__ u32 wps[NW], wpo[NW];
    __shared__ ulonglong2 sE[ENT_LDS];
    __shared__ u32 s_n, s_nk;
    __shared__ int chg;

    if (t == 0) { u32 nn = *cursor; if (nn > ENT_CAP) nn = ENT_CAP; s_n = nn; }
    if (t < NW) { kw[t] = ~0ULL; ko[t] = 0ULL; }
    __syncthreads();
    u32 n = s_n;
    bool fits = (n <= (u32)ENT_LDS);
    if (fits) for (u32 e = t; e < n; e += 256) sE[e] = ent[e];
    // staging completes before first use: sync A below

    for (int iter = 0; iter < NBOX; ++iter) {
        if (t < NW) sup[t] = 0ULL;
        if (t == 0) chg = 0;
        __syncthreads();                              // A
        for (u32 e = t; e < n; e += 256) {
            ulonglong2 E = fits ? sE[e] : ent[e];
            u32 meta = (u32)E.y;
            u32 ej = meta >> 7, ew = meta & 127u;
            if (E.x & kw[ew]) atomicOr(&sup[ej >> 6], 1ULL << (ej & 63u));
        }
        __syncthreads();                              // B
        if (t < NW) {
            u64 nk = ~sup[t];
            if (nk != kw[t]) { kw[t] = nk; chg = 1; } // benign same-value race
        }
        __syncthreads();                              // C
        int dn = !chg;
        __syncthreads();                              // D
        if (dn) break;
    }

    // kept bitmap in ORIGINAL order
    for (int r = t; r < NBOX; r += 256) {
        if ((kw[r >> 6] >> (r & 63)) & 1ULL) {
            int j = order[r];
            atomicOr(&ko[j >> 6], 1ULL << (j & 63));
        }
    }
    __syncthreads();
    // wave 0: word-prefix popcount scans via shuffles
    if (t < 64) {
        int l = t;
        u32 a0 = (u32)__popcll(kw[2 * l]), a1 = (u32)__popcll(kw[2 * l + 1]);
        u32 s = a0 + a1;
        for (int d = 1; d < 64; d <<= 1) { u32 v = __shfl_up(s, d, 64); if (l >= d) s += v; }
        u32 ex = s - a0 - a1;
        wps[2 * l] = ex; wps[2 * l + 1] = ex + a0;
        if (l == 63) s_nk = s;
        u32 b0 = (u32)__popcll(ko[2 * l]), b1 = (u32)__popcll(ko[2 * l + 1]);
        u32 so = b0 + b1;
        for (int d = 1; d < 64; d <<= 1) { u32 v = __shfl_up(so, d, 64); if (l >= d) so += v; }
        u32 exo = so - b0 - b1;
        wpo[2 * l] = exo; wpo[2 * l + 1] = exo + b0;
    }
    __syncthreads();
    u32 nk = s_nk;

    // ---- phase 3 (same block): final placement + output ----
    // kept: pos = rank among kept (sorted order); suppressed: pos = nk + rank among suppressed by original idx
    for (int r = t; r < NBOX; r += 256) {
        int j = order[r];
        u64 kwrd = kw[r >> 6];
        bool kept = (kwrd >> (r & 63)) & 1ULL;
        u32 pos;
        if (kept) {
            pos = wps[r >> 6] + (u32)__popcll(kwrd & ((1ULL << (r & 63)) - 1ULL));
        } else {
            u64 ow = ko[j >> 6];
            u32 prefO = wpo[j >> 6] + (u32)__popcll(ow & ((1ULL << (j & 63)) - 1ULL));
            pos = nk + (u32)j - prefO;
        }
        float4 bx = boxes4[j];
        float s = kept ? scores[j] : 0.0f;
        out[pos * 5 + 0] = bx.x;
        out[pos * 5 + 1] = bx.y;
        out[pos * 5 + 2] = bx.z;
        out[pos * 5 + 3] = bx.w;
        out[pos * 5 + 4] = s;
        out[NBOX * 5 + pos] = (float)j;
    }
}

extern "C" void kernel_launch(void* const* d_in, const int* in_sizes, int n_in,
                              void* d_out, int out_size, void* d_ws, size_t ws_size,
                              hipStream_t stream) {
    const float* boxes  = (const float*)d_in[0];
    const float* scores = (const float*)d_in[1];
    const int*   idxs   = (const int*)d_in[2];
    float* out = (float*)d_out;

    char* w = (char*)d_ws;
    float4*     sb        = (float4*)    (w + 0);         // 131072 (16B aligned)
    ulonglong2* ent       = (ulonglong2*)(w + 131072);    // 1048576 (16B aligned)
    int*        rank_part = (int*)       (w + 1179648);   // 262144
    float*      area      = (float*)     (w + 1441792);   //  32768
    int*        order     = (int*)       (w + 1474560);   //  32768
    float*      blockmax  = (float*)     (w + 1507328);   //   1024
    u32*        cursor    = (u32*)       (w + 1508352);   //      4
    u32*        done      = (u32*)       (w + 1508356);   //      4

    k_prep<<<256, 256, 0, stream>>>(scores, boxes, rank_part, blockmax, cursor, done);
    k_sgather<<<32, 256, 0, stream>>>((const float4*)boxes, idxs, rank_part, blockmax, sb, area, order);
    k_mask_tail<<<MASK_BLOCKS, 256, 0, stream>>>(sb, area, order, (const float4*)boxes, scores,
                                                 ent, cursor, done, out);
}

// Round 6
// 62.760 us; speedup vs baseline: 2.0582x; 2.0582x over previous
//
#include <hip/hip_runtime.h>
#include <stdint.h>

#define NBOX 8192
#define NW   128            // NBOX/64 words
#define IOU_THR 0.45f
#define ENT_CAP 65536u      // global entry capacity
#define ENT_LDS 2560        // LDS-staged entry capacity (40 KB)

typedef unsigned long long u64;
typedef unsigned int u32;

// ---------------- K1: rank parts + per-block box max + cursor zero ----------------
// key = (~bits(score))<<32 | idx : ascending == (score desc, idx asc) == stable argsort(-scores)
// Keys computed LOCALLY from scores (pure function) -> no producer kernel needed.
// rank_part[ip][j] written non-atomically -> no zero-init needed.
__global__ void __launch_bounds__(256) k_prep(const float* __restrict__ scores,
                                              const float* __restrict__ boxes,
                                              int* __restrict__ rank_part,
                                              float* __restrict__ blockmax,
                                              u32* __restrict__ cursor) {
    __shared__ u64 lk[1024];
    __shared__ float red[128];
    int t = threadIdx.x, b = blockIdx.x;
    int jc = b & 31, ip = b >> 5;
    for (int i = t; i < 1024; i += 256) {
        int gi = ip * 1024 + i;
        lk[i] = ((u64)(~__float_as_uint(scores[gi])) << 32) | (u32)gi;
    }
    if (t < 128) red[t] = boxes[b * 128 + t];     // 256 blocks x 128 = all 32768 coords
    __syncthreads();
    int j = jc * 256 + t;
    u64 kj = ((u64)(~__float_as_uint(scores[j])) << 32) | (u32)j;
    int cnt = 0;
#pragma unroll 8
    for (int i = 0; i < 1024; ++i) cnt += (lk[i] < kj) ? 1 : 0;
    rank_part[ip * NBOX + j] = cnt;
    // reduce 128 -> blockmax[b]
    if (t < 64) red[t] = fmaxf(red[t], red[t + 64]);
    __syncthreads();
    if (t < 64) {
        float m = red[t];
        for (int d = 32; d > 0; d >>= 1) m = fmaxf(m, __shfl_down(m, d, 64));
        if (t == 0) blockmax[b] = m;
    }
    if (b == 0 && t == 0) *cursor = 0u;
}

// ---------------- K2: scatter-gather: sb[rank[j]] = offset-box(j), + sorted classes ----------------
__global__ void __launch_bounds__(256) k_sgather(const float4* __restrict__ boxes4,
                                                 const int* __restrict__ idxs,
                                                 const int* __restrict__ rank_part,
                                                 const float* __restrict__ blockmax,
                                                 float4* __restrict__ sb, float* __restrict__ area,
                                                 int* __restrict__ order, int* __restrict__ scls) {
    __shared__ float red[256];
    int t = threadIdx.x;
    red[t] = blockmax[t];
    __syncthreads();
    for (int s = 128; s > 0; s >>= 1) {
        if (t < s) red[t] = fmaxf(red[t], red[t + s]);
        __syncthreads();
    }
    float mc1 = red[0] + 1.0f;
    int j = blockIdx.x * 256 + t;
    int r = 0;
#pragma unroll
    for (int p = 0; p < 8; ++p) r += rank_part[p * NBOX + j];
    float4 bx = boxes4[j];
    int c = idxs[j];
    float off = (float)c * mc1;
    bx.x += off; bx.y += off; bx.z += off; bx.w += off;
    sb[r] = bx;
    area[r] = (bx.z - bx.x) * (bx.w - bx.y);   // area on OFFSET boxes, exactly like ref
    order[r] = j;
    scls[r] = c;
}

// ---------------- K3: sparse overlap mask with class early-out ----------------
// entry.x = word (bit b = over(i=64w+b, j), i<j) ; entry.y = (j<<7)|w
// Different classes are EXACTLY disjoint after offsetting (gap >= 1.0 >> f32 rounding
// at ~88K), so class(i) != class(j) => inter == 0 => never over. Exactness preserved.
__global__ void __launch_bounds__(256) k_mask(const float4* __restrict__ sb,
                                              const float* __restrict__ area,
                                              const int* __restrict__ scls,
                                              ulonglong2* __restrict__ ent, u32* __restrict__ cursor) {
    __shared__ float4 ib[64];
    __shared__ float  ia[64];
    __shared__ int    ic[64];
    int w = blockIdx.x;                       // 0..127
    int j = blockIdx.y * 256 + threadIdx.x;   // 0..8191
    if (threadIdx.x < 64) {
        ib[threadIdx.x] = sb[w * 64 + threadIdx.x];
        ia[threadIdx.x] = area[w * 64 + threadIdx.x];
        ic[threadIdx.x] = scls[w * 64 + threadIdx.x];
    }
    __syncthreads();
    if (w * 64 >= j) return;                  // no i<j in this word
    float4 bj = sb[j];
    float  aj = area[j];
    int    cj = scls[j];
    u64 word = 0;
    int nb = min(64, j - w * 64);
    for (int bb = 0; bb < nb; ++bb) {
        if (ic[bb] == cj) {                   // cross-class pairs provably inter==0
            float4 bi = ib[bb];
            float ltx = fmaxf(bi.x, bj.x), lty = fmaxf(bi.y, bj.y);
            float rbx = fminf(bi.z, bj.z), rby = fminf(bi.w, bj.w);
            float wx = fmaxf(rbx - ltx, 0.0f), wy = fmaxf(rby - lty, 0.0f);
            float inter = wx * wy;
            if (inter > 0.0f) {
                float iou = inter / (ia[bb] + aj - inter);   // IEEE f32 div, matches ref
                if (iou > IOU_THR) word |= (1ULL << bb);
            }
        }
    }
    if (word) {
        u32 idx = atomicAdd(cursor, 1u);
        if (idx < ENT_CAP) {
            ulonglong2 e; e.x = word; e.y = (u64)(((u32)j << 7) | (u32)w);
            ent[idx] = e;
        }
    }
}

// ---------------- K4: single-block {Jacobi fixpoint + placement + output} ----------------
// kept[j] = !exists i<j : kept[i] && over(i,j). Unique fixpoint; Jacobi iterate until
// stable — stability certifies the exact greedy answer. Same block => no fences needed.
__global__ void __launch_bounds__(1024)
k_tail(const ulonglong2* __restrict__ ent, const u32* __restrict__ cursor,
       const int* __restrict__ order, const float4* __restrict__ boxes4,
       const float* __restrict__ scores, float* __restrict__ out) {
    __shared__ u64 kw[NW], sup[NW], ko[NW];
    __shared__ u32 wps[NW], wpo[NW];
    __shared__ ulonglong2 sE[ENT_LDS];
    __shared__ u32 s_n, s_nk;
    __shared__ int chg;

    int t = threadIdx.x;
    if (t == 0) { u32 nn = *cursor; if (nn > ENT_CAP) nn = ENT_CAP; s_n = nn; }
    if (t < NW) { kw[t] = ~0ULL; ko[t] = 0ULL; }
    __syncthreads();
    u32 n = s_n;
    bool fits = (n <= (u32)ENT_LDS);
    if (fits) for (u32 e = t; e < n; e += 1024) sE[e] = ent[e];
    // staging completes before first use: sync A below

    for (int iter = 0; iter < NBOX; ++iter) {
        if (t < NW) sup[t] = 0ULL;
        if (t == 0) chg = 0;
        __syncthreads();                              // A
        for (u32 e = t; e < n; e += 1024) {
            ulonglong2 E = fits ? sE[e] : ent[e];
            u32 meta = (u32)E.y;
            u32 ej = meta >> 7, ew = meta & 127u;
            if (E.x & kw[ew]) atomicOr(&sup[ej >> 6], 1ULL << (ej & 63u));
        }
        __syncthreads();                              // B
        if (t < NW) {
            u64 nk = ~sup[t];
            if (nk != kw[t]) { kw[t] = nk; chg = 1; } // benign same-value race
        }
        __syncthreads();                              // C
        int dn = !chg;
        __syncthreads();                              // D
        if (dn) break;
    }

    // kept bitmap in ORIGINAL order
    for (int r = t; r < NBOX; r += 1024) {
        if ((kw[r >> 6] >> (r & 63)) & 1ULL) {
            int j = order[r];
            atomicOr(&ko[j >> 6], 1ULL << (j & 63));
        }
    }
    __syncthreads();
    // wave 0: word-prefix popcount scans via shuffles
    if (t < 64) {
        int l = t;
        u32 a0 = (u32)__popcll(kw[2 * l]), a1 = (u32)__popcll(kw[2 * l + 1]);
        u32 s = a0 + a1;
        for (int d = 1; d < 64; d <<= 1) { u32 v = __shfl_up(s, d, 64); if (l >= d) s += v; }
        u32 ex = s - a0 - a1;
        wps[2 * l] = ex; wps[2 * l + 1] = ex + a0;
        if (l == 63) s_nk = s;
        u32 b0 = (u32)__popcll(ko[2 * l]), b1 = (u32)__popcll(ko[2 * l + 1]);
        u32 so = b0 + b1;
        for (int d = 1; d < 64; d <<= 1) { u32 v = __shfl_up(so, d, 64); if (l >= d) so += v; }
        u32 exo = so - b0 - b1;
        wpo[2 * l] = exo; wpo[2 * l + 1] = exo + b0;
    }
    __syncthreads();
    u32 nk = s_nk;

    // final placement + output:
    // kept: pos = rank among kept (sorted order) == stable argsort of scores-after-nms
    // suppressed (score 0): pos = nk + rank among suppressed by ORIGINAL index
    for (int r = t; r < NBOX; r += 1024) {
        int j = order[r];
        u64 kwrd = kw[r >> 6];
        bool kept = (kwrd >> (r & 63)) & 1ULL;
        u32 pos;
        if (kept) {
            pos = wps[r >> 6] + (u32)__popcll(kwrd & ((1ULL << (r & 63)) - 1ULL));
        } else {
            u64 ow = ko[j >> 6];
            u32 prefO = wpo[j >> 6] + (u32)__popcll(ow & ((1ULL << (j & 63)) - 1ULL));
            pos = nk + (u32)j - prefO;
        }
        float4 bx = boxes4[j];
        float s = kept ? scores[j] : 0.0f;
        out[pos * 5 + 0] = bx.x;
        out[pos * 5 + 1] = bx.y;
        out[pos * 5 + 2] = bx.z;
        out[pos * 5 + 3] = bx.w;
        out[pos * 5 + 4] = s;
        out[NBOX * 5 + pos] = (float)j;
    }
}

extern "C" void kernel_launch(void* const* d_in, const int* in_sizes, int n_in,
                              void* d_out, int out_size, void* d_ws, size_t ws_size,
                              hipStream_t stream) {
    const float* boxes  = (const float*)d_in[0];
    const float* scores = (const float*)d_in[1];
    const int*   idxs   = (const int*)d_in[2];
    float* out = (float*)d_out;

    char* w = (char*)d_ws;
    float4*     sb        = (float4*)    (w + 0);         // 131072 (16B aligned)
    ulonglong2* ent       = (ulonglong2*)(w + 131072);    // 1048576 (16B aligned)
    int*        rank_part = (int*)       (w + 1179648);   // 262144
    float*      area      = (float*)     (w + 1441792);   //  32768
    int*        order     = (int*)       (w + 1474560);   //  32768
    int*        scls      = (int*)       (w + 1507328);   //  32768
    float*      blockmax  = (float*)     (w + 1540096);   //   1024
    u32*        cursor    = (u32*)       (w + 1541120);   //      4

    k_prep<<<256, 256, 0, stream>>>(scores, boxes, rank_part, blockmax, cursor);
    k_sgather<<<32, 256, 0, stream>>>((const float4*)boxes, idxs, rank_part, blockmax,
                                      sb, area, order, scls);
    dim3 gm(128, 32);
    k_mask<<<gm, 256, 0, stream>>>(sb, area, scls, ent, cursor);
    k_tail<<<1, 1024, 0, stream>>>(ent, cursor, order, (const float4*)boxes, scores, out);
}

// Round 7
// 52.066 us; speedup vs baseline: 2.4810x; 1.2054x over previous
//
#include <hip/hip_runtime.h>
#include <stdint.h>

#define NBOX 8192
#define NW   128            // NBOX/64 words
#define IOU_THR 0.45f
#define ENT_CAP 65536u      // global entry capacity
#define ENT_LDS 2560        // LDS-staged entry capacity (40 KB)
#define TAIL_BLOCKS 8

typedef unsigned long long u64;
typedef unsigned int u32;
typedef unsigned short u16;

// ---------------- K1: rank parts + per-block box max + cursor zero ----------------
// key = (~bits(score))<<32 | idx : ascending == (score desc, idx asc) == stable argsort(-scores)
// rank_part[ip][j] written non-atomically -> no zero-init needed.
__global__ void __launch_bounds__(256) k_prep(const float* __restrict__ scores,
                                              const float* __restrict__ boxes,
                                              int* __restrict__ rank_part,
                                              float* __restrict__ blockmax,
                                              u32* __restrict__ cursor) {
    __shared__ u64 lk[1024];
    __shared__ float red[128];
    int t = threadIdx.x, b = blockIdx.x;
    int jc = b & 31, ip = b >> 5;
    for (int i = t; i < 1024; i += 256) {
        int gi = ip * 1024 + i;
        lk[i] = ((u64)(~__float_as_uint(scores[gi])) << 32) | (u32)gi;
    }
    if (t < 128) red[t] = boxes[b * 128 + t];     // 256 blocks x 128 = all 32768 coords
    __syncthreads();
    int j = jc * 256 + t;
    u64 kj = ((u64)(~__float_as_uint(scores[j])) << 32) | (u32)j;
    int cnt = 0;
#pragma unroll 8
    for (int i = 0; i < 1024; ++i) cnt += (lk[i] < kj) ? 1 : 0;
    rank_part[ip * NBOX + j] = cnt;
    if (t < 64) red[t] = fmaxf(red[t], red[t + 64]);
    __syncthreads();
    if (t < 64) {
        float m = red[t];
        for (int d = 32; d > 0; d >>= 1) m = fmaxf(m, __shfl_down(m, d, 64));
        if (t == 0) blockmax[b] = m;
    }
    if (b == 0 && t == 0) *cursor = 0u;
}

// ---------------- K2: sparse overlap mask in ORIGINAL order, offsets on the fly ----------------
// entry.x = word (bit b = over(i=64w+b, j), i<j original order) ; entry.y = (j<<7)|w
// Different classes are EXACTLY disjoint after offsetting (gap >= 1.0 >> f32 rounding
// at ~88K), so class(i) != class(j) => inter == 0 => never over. Exactness preserved.
__global__ void __launch_bounds__(256) k_mask(const float4* __restrict__ boxes4,
                                              const int* __restrict__ idxs,
                                              const float* __restrict__ blockmax,
                                              ulonglong2* __restrict__ ent, u32* __restrict__ cursor) {
    __shared__ float4 ib[64];
    __shared__ float  ia[64];
    __shared__ int    ic[64];
    __shared__ float  red[256];
    int t = threadIdx.x;
    int w = blockIdx.x;                       // 0..127 (i-word)
    int jb = blockIdx.y * 256;                // j-chunk base
    if (w * 64 >= jb + 255) return;           // uniform: no i<j anywhere in this tile

    red[t] = blockmax[t];
    __syncthreads();
    for (int s = 128; s > 0; s >>= 1) {
        if (t < s) red[t] = fmaxf(red[t], red[t + s]);
        __syncthreads();
    }
    float mc1 = red[0] + 1.0f;

    if (t < 64) {
        int i = w * 64 + t;
        float4 bi = boxes4[i];
        int c = idxs[i];
        float off = (float)c * mc1;
        bi.x += off; bi.y += off; bi.z += off; bi.w += off;
        ib[t] = bi;
        ia[t] = (bi.z - bi.x) * (bi.w - bi.y);   // area on OFFSET boxes, exactly like ref
        ic[t] = c;
    }
    __syncthreads();
    int j = jb + t;
    if (w * 64 >= j) return;                  // per-thread triangle skip
    float4 bj = boxes4[j];
    int cj = idxs[j];
    float offj = (float)cj * mc1;
    bj.x += offj; bj.y += offj; bj.z += offj; bj.w += offj;
    float aj = (bj.z - bj.x) * (bj.w - bj.y);
    u64 word = 0;
    int nb = min(64, j - w * 64);
    for (int bb = 0; bb < nb; ++bb) {
        if (ic[bb] == cj) {                   // cross-class pairs provably inter==0
            float4 bi = ib[bb];
            float ltx = fmaxf(bi.x, bj.x), lty = fmaxf(bi.y, bj.y);
            float rbx = fminf(bi.z, bj.z), rby = fminf(bi.w, bj.w);
            float wx = fmaxf(rbx - ltx, 0.0f), wy = fmaxf(rby - lty, 0.0f);
            float inter = wx * wy;
            if (inter > 0.0f) {
                float iou = inter / (ia[bb] + aj - inter);   // IEEE f32 div, matches ref
                if (iou > IOU_THR) word |= (1ULL << bb);
            }
        }
    }
    if (word) {
        u32 idx = atomicAdd(cursor, 1u);
        if (idx < ENT_CAP) {
            ulonglong2 e; e.x = word; e.y = (u64)(((u32)j << 7) | (u32)w);
            ent[idx] = e;
        }
    }
}

// ---------------- K3: replicated {rank LUT + oriented Jacobi} + parallel output ----------------
// Each of the TAIL_BLOCKS blocks redundantly computes the full (small, all-LDS) resolve,
// then outputs its own 1024-box slice. Redundant compute instead of cross-block sync.
// kept[j] = !exists i (rank[i]<rank[j]) : kept[i] && over(i,j). Unique fixpoint; Jacobi
// iterate until stable — stability certifies the exact greedy answer.
__global__ void __launch_bounds__(1024)
k_tail(const ulonglong2* __restrict__ ent, const u32* __restrict__ cursor,
       const int* __restrict__ rank_part, const float4* __restrict__ boxes4,
       const float* __restrict__ scores, u64* __restrict__ gLT, float* __restrict__ out) {
    __shared__ ulonglong2 sE[ENT_LDS];        // 40 KB
    __shared__ u64 sLT[ENT_LDS];              // 20 KB
    __shared__ u16 rank16[NBOX];              // 16 KB
    __shared__ u64 kw[NW], sup[NW], kws[NW];  // kept(orig), suppress scratch, kept(sorted)
    __shared__ u32 wps[NW], wpo[NW];
    __shared__ u32 s_n, s_nk;
    __shared__ int chg;

    int t = threadIdx.x;
    if (t == 0) { u32 nn = *cursor; if (nn > ENT_CAP) nn = ENT_CAP; s_n = nn; }
    if (t < NW) { kw[t] = ~0ULL; kws[t] = 0ULL; }
    for (int j = t; j < NBOX; j += 1024) {
        int r = 0;
#pragma unroll
        for (int p = 0; p < 8; ++p) r += rank_part[p * NBOX + j];
        rank16[j] = (u16)r;
    }
    __syncthreads();
    u32 n = s_n;
    bool fits = (n <= (u32)ENT_LDS);

    // stage entries + orient each bit by rank (lt bit set <=> i has higher priority than j)
    for (u32 e = t; e < n; e += 1024) {
        ulonglong2 E = ent[e];
        u32 meta = (u32)E.y;
        u32 ej = meta >> 7, ew = meta & 127u;
        u32 rj = rank16[ej];
        u64 lt = 0, wrem = E.x;
        while (wrem) {
            int bb = __ffsll(wrem) - 1;
            wrem &= wrem - 1;
            if (rank16[ew * 64 + bb] < rj) lt |= (1ULL << bb);
        }
        if (fits) { sE[e] = E; sLT[e] = lt; }
        else      { gLT[e] = lt; }            // all blocks write identical values: benign
    }
    __syncthreads();

    for (int iter = 0; iter < NBOX; ++iter) {
        if (t < NW) sup[t] = 0ULL;
        if (t == 0) chg = 0;
        __syncthreads();                              // A
        for (u32 e = t; e < n; e += 1024) {
            ulonglong2 E = fits ? sE[e] : ent[e];
            u64 lt      = fits ? sLT[e] : gLT[e];
            u32 meta = (u32)E.y;
            u32 ej = meta >> 7, ew = meta & 127u;
            u64 word = E.x;
            if (word & lt & kw[ew])                      // kept higher-priority i overlaps j
                atomicOr(&sup[ej >> 6], 1ULL << (ej & 63u));
            u64 rev = word & ~lt;                        // i's that j outranks
            if (rev && ((kw[ej >> 6] >> (ej & 63u)) & 1ULL))
                atomicOr(&sup[ew], rev);
        }
        __syncthreads();                              // B
        if (t < NW) {
            u64 nk2 = ~sup[t];
            if (nk2 != kw[t]) { kw[t] = nk2; chg = 1; } // benign same-value race
        }
        __syncthreads();                              // C
        int dn = !chg;
        __syncthreads();                              // D
        if (dn) break;
    }

    // kept bitmap in SORTED order (for kept-rank placement)
    for (int j = t; j < NBOX; j += 1024) {
        if ((kw[j >> 6] >> (j & 63)) & 1ULL) {
            u32 r = rank16[j];
            atomicOr(&kws[r >> 6], 1ULL << (r & 63u));
        }
    }
    __syncthreads();
    // wave 0: word-prefix popcount scans via shuffles
    if (t < 64) {
        int l = t;
        u32 a0 = (u32)__popcll(kws[2 * l]), a1 = (u32)__popcll(kws[2 * l + 1]);
        u32 s = a0 + a1;
        for (int d = 1; d < 64; d <<= 1) { u32 v = __shfl_up(s, d, 64); if (l >= d) s += v; }
        u32 ex = s - a0 - a1;
        wps[2 * l] = ex; wps[2 * l + 1] = ex + a0;
        if (l == 63) s_nk = s;
        u32 b0 = (u32)__popcll(kw[2 * l]), b1 = (u32)__popcll(kw[2 * l + 1]);
        u32 so = b0 + b1;
        for (int d = 1; d < 64; d <<= 1) { u32 v = __shfl_up(so, d, 64); if (l >= d) so += v; }
        u32 exo = so - b0 - b1;
        wpo[2 * l] = exo; wpo[2 * l + 1] = exo + b0;
    }
    __syncthreads();
    u32 nk = s_nk;

    // parallel output: this block's 1024-box slice (coalesced reads, scattered writes)
    // kept: pos = rank among kept (score desc, idx asc). suppressed: pos = nk + rank by orig idx.
    int j = blockIdx.x * 1024 + t;
    if (j < NBOX) {
        bool kept = (kw[j >> 6] >> (j & 63)) & 1ULL;
        u32 pos;
        if (kept) {
            u32 r = rank16[j];
            pos = wps[r >> 6] + (u32)__popcll(kws[r >> 6] & ((1ULL << (r & 63)) - 1ULL));
        } else {
            u32 prefO = wpo[j >> 6] + (u32)__popcll(kw[j >> 6] & ((1ULL << (j & 63)) - 1ULL));
            pos = nk + (u32)j - prefO;
        }
        float4 bx = boxes4[j];
        float s = kept ? scores[j] : 0.0f;
        out[pos * 5 + 0] = bx.x;
        out[pos * 5 + 1] = bx.y;
        out[pos * 5 + 2] = bx.z;
        out[pos * 5 + 3] = bx.w;
        out[pos * 5 + 4] = s;
        out[NBOX * 5 + pos] = (float)j;
    }
}

extern "C" void kernel_launch(void* const* d_in, const int* in_sizes, int n_in,
                              void* d_out, int out_size, void* d_ws, size_t ws_size,
                              hipStream_t stream) {
    const float* boxes  = (const float*)d_in[0];
    const float* scores = (const float*)d_in[1];
    const int*   idxs   = (const int*)d_in[2];
    float* out = (float*)d_out;

    char* w = (char*)d_ws;
    ulonglong2* ent       = (ulonglong2*)(w + 0);         // 1048576 (16B aligned)
    u64*        gLT       = (u64*)       (w + 1048576);   // 524288
    int*        rank_part = (int*)       (w + 1572864);   // 262144
    float*      blockmax  = (float*)     (w + 1835008);   //   1024
    u32*        cursor    = (u32*)       (w + 1836032);   //      4

    k_prep<<<256, 256, 0, stream>>>(scores, boxes, rank_part, blockmax, cursor);
    dim3 gm(128, 32);
    k_mask<<<gm, 256, 0, stream>>>((const float4*)boxes, idxs, blockmax, ent, cursor);
    k_tail<<<TAIL_BLOCKS, 1024, 0, stream>>>(ent, cursor, rank_part, (const float4*)boxes,
                                             scores, gLT, out);
}